// Round 2
// 348.236 us; speedup vs baseline: 1.0174x; 1.0174x over previous
//
#include <hip/hip_runtime.h>
#include <stdint.h>

// Problem constants: x[4,64,256,512] fp32, idx[3*256*3*512] i32 (harness converts i64->i32),
// w[64,64,3,3] fp32, bias[64] fp32. out[4,64,256,512] fp32.
#define HW_   131072   // 256*512 = 1<<17
#define W_    512
#define C_    64
#define KDIM  576      // 9 taps * 64 channels

typedef __bf16 bf16_t;
typedef bf16_t bf16x8 __attribute__((ext_vector_type(8)));
typedef float  f32x4_t __attribute__((ext_vector_type(4)));
typedef float  f32x2_t __attribute__((ext_vector_type(2)));

__device__ __forceinline__ unsigned short f32_to_bf16(float f) {
    union { float f; unsigned u; } v; v.f = f;
    unsigned r = (v.u + 0x7FFFu + ((v.u >> 16) & 1u)) >> 16;  // RNE
    return (unsigned short)r;
}

// Pack two f32 -> two bf16 in one dword via compiler casts (RNE). Per m240, the
// compiler handles bf16 convert well; no inline asm needed.
__device__ __forceinline__ unsigned pack_bf16(float a, float b) {
    union { unsigned u; __bf16 h[2]; } pk;
    pk.h[0] = (__bf16)a;
    pk.h[1] = (__bf16)b;
    return pk.u;
}

// ws layout: xt bf16 [B*HW][64] at offset 0 (67,108,864 B); Wfrag bf16 at +XT_BYTES (73,728 B)
#define XT_BYTES   67108864ull
#define WF_BYTES   73728ull

// ---------------------------------------------------------------------------
// Pack weight[o][c][kh][kw] fp32 -> B-operand fragments, K-order k = t*64 + c, t = kh*3+kw.
// Fragment (kc, nt): lane L holds B[k = kc*32 + (L>>4)*8 + j][n = nt*16 + (L&15)], j=0..7.
// ---------------------------------------------------------------------------
__global__ __launch_bounds__(256) void k_prep_w(const float* __restrict__ w,
                                                unsigned short* __restrict__ wfrag) {
    int id = blockIdx.x * 256 + threadIdx.x;   // (kc*4 + nt)*64 + lane, total 18*4*64 = 4608
    if (id >= 18 * 4 * 64) return;
    int lane = id & 63;
    int nt   = (id >> 6) & 3;
    int kc   = id >> 8;
    int n  = nt * 16 + (lane & 15);
    int k0 = kc * 32 + ((lane >> 4) << 3);
    unsigned short tmp[8];
#pragma unroll
    for (int j = 0; j < 8; ++j) {
        int k = k0 + j;
        int t = k >> 6;    // tap 0..8
        int c = k & 63;
        tmp[j] = f32_to_bf16(w[(size_t)n * KDIM + c * 9 + t]);
    }
    uint4 v;
    v.x = tmp[0] | ((unsigned)tmp[1] << 16);
    v.y = tmp[2] | ((unsigned)tmp[3] << 16);
    v.z = tmp[4] | ((unsigned)tmp[5] << 16);
    v.w = tmp[6] | ((unsigned)tmp[7] << 16);
    ((uint4*)wfrag)[id] = v;
}

// ---------------------------------------------------------------------------
// Transpose + convert via LDS: x[b][c][p] fp32 -> xt[(b*HW+p)][c] bf16.
// Phase 1: float2 nontemporal reads (8 B/lane, 512 B/wave-instr), packed bf16 convert,
//          ds_write_b32; tile row stride 66 shorts (33 dwords == 1 mod 32).
// Phase 2: row-major reads conflict-light, coalesced lane-contiguous 16 B stores.
// x is read exactly once -> nontemporal loads keep L2/L3 space for xt (gemm re-reads it).
// ---------------------------------------------------------------------------
__global__ __launch_bounds__(256) void k_transpose(const float* __restrict__ x,
                                                   unsigned short* __restrict__ xt) {
    __shared__ unsigned short tile[256][66];
    int t    = threadIdx.x;
    int lane = t & 63;
    int wave = t >> 6;
    int gp0 = blockIdx.x * 256;                // grid = 2048
    int b  = gp0 >> 17;
    int p0 = gp0 & (HW_ - 1);
    const float* xb = x + ((size_t)b * C_) * HW_ + p0;
#pragma unroll
    for (int it = 0; it < 16; ++it) {
        int c0  = (it & 7) * 8 + wave * 2;     // even channels 0..62, 2 per thread
        int px0 = ((it >> 3) << 7) + lane * 2; // 2 consecutive pixels per thread
        const float* s0 = xb + ((size_t)c0 << 17) + px0;
        f32x2_t v0 = __builtin_nontemporal_load((const f32x2_t*)s0);
        f32x2_t v1 = __builtin_nontemporal_load((const f32x2_t*)(s0 + HW_));
        *(unsigned*)&tile[px0 + 0][c0] = pack_bf16(v0.x, v1.x);
        *(unsigned*)&tile[px0 + 1][c0] = pack_bf16(v0.y, v1.y);
    }
    __syncthreads();
    unsigned short* dst = xt + (size_t)gp0 * C_;
#pragma unroll
    for (int it = 0; it < 8; ++it) {
        int cid = it * 256 + t;        // 2048 chunks of 16 B
        int px  = cid >> 3;
        int ch  = cid & 7;
        uint4 v;
        v.x = *(unsigned*)&tile[px][ch * 8 + 0];
        v.y = *(unsigned*)&tile[px][ch * 8 + 2];
        v.z = *(unsigned*)&tile[px][ch * 8 + 4];
        v.w = *(unsigned*)&tile[px][ch * 8 + 6];
        ((uint4*)(dst + (size_t)px * C_))[ch] = v;   // lane-contiguous across the wave
    }
}

// ---------------------------------------------------------------------------
// Gather-GEMM, software-pipelined. Per wave: M=32 pixels x N=64, K=576.
// 18 half-K steps (s = kc), 3-stage rotating register buffers. Gather indices in registers.
// Grid 4096 x 256 threads; block covers 128 consecutive pixels (same batch).
// XCD-chunked blockIdx swizzle (4096 % 8 == 0, bijective): co-resident blocks per XCD
// share one batch image and write contiguous output regions.
// Output stores are nontemporal (never re-read) so they don't evict xt from L2/L3.
// ---------------------------------------------------------------------------
__global__ __launch_bounds__(256) void k_gemm(const unsigned short* __restrict__ xt,
                                              const unsigned short* __restrict__ wfrag,
                                              const int* __restrict__ idx,
                                              const float* __restrict__ bias,
                                              float* __restrict__ out) {
    __shared__ unsigned p_lds[128][9];   // 4608 B

    int tid  = threadIdx.x;
    int wave = tid >> 6;
    int lane = tid & 63;
    int bid  = blockIdx.x;
    int gbase = (((bid & 7) << 9) + (bid >> 3)) * 128;  // XCD-chunked swizzle
    int b = gbase >> 17;

    // Stage gather indices: 2 threads per pixel (128 px * 9 taps)
    {
        int px   = tid >> 1;
        int half = tid & 1;
        int g  = gbase + px;
        int hw = g & (HW_ - 1);
        int h = hw >> 9, w = hw & (W_ - 1);
        size_t base = (size_t)(3 * h) * (3 * W_) + 3 * w;
        if (half == 0) {
#pragma unroll
            for (int t = 0; t < 5; ++t)
                p_lds[px][t] = (unsigned)idx[base + (size_t)(t / 3) * (3 * W_) + (t % 3)];
        } else {
#pragma unroll
            for (int t = 5; t < 9; ++t)
                p_lds[px][t] = (unsigned)idx[base + (size_t)(t / 3) * (3 * W_) + (t % 3)];
        }
    }
    __syncthreads();

    int quad = lane >> 4;
    int col  = lane & 15;
    int pxw  = wave * 32;

    // Hoist this lane's 18 gather indices into registers
    unsigned p_reg[9][2];
#pragma unroll
    for (int t = 0; t < 9; ++t) {
        p_reg[t][0] = p_lds[pxw + col][t];
        p_reg[t][1] = p_lds[pxw + 16 + col][t];
    }

    const unsigned short* xtb = xt + (((size_t)b) << 17) * C_;
    const uint4* wf = (const uint4*)wfrag;

    f32x4_t acc[2][4] = {};
    bf16x8 Abuf[3][2];
    bf16x8 Bbuf[3][4];

    // load step s (= kc): A frag per ms at row p_reg[s>>1][ms], byte off (s&1)*64 + quad*16
    // B frags (s*4+nt)*64 + lane
#define ISSUE(s, slot)                                                              \
    {                                                                               \
        const int t_ = (s) >> 1, h_ = (s) & 1;                                      \
        _Pragma("unroll")                                                           \
        for (int ms = 0; ms < 2; ++ms) {                                            \
            const uint4* ap = (const uint4*)((const char*)xtb +                     \
                ((size_t)p_reg[t_][ms] << 7) + (h_ << 6) + (quad << 4));            \
            Abuf[slot][ms] = __builtin_bit_cast(bf16x8, *ap);                       \
        }                                                                           \
        _Pragma("unroll")                                                           \
        for (int nt = 0; nt < 4; ++nt)                                              \
            Bbuf[slot][nt] = __builtin_bit_cast(bf16x8, wf[((s) * 4 + nt) * 64 + lane]); \
    }

    ISSUE(0, 0)
    ISSUE(1, 1)
    ISSUE(2, 2)
#pragma unroll
    for (int s = 0; s < 18; ++s) {
        const int slot = s % 3;
#pragma unroll
        for (int ms = 0; ms < 2; ++ms)
#pragma unroll
            for (int nt = 0; nt < 4; ++nt)
                acc[ms][nt] = __builtin_amdgcn_mfma_f32_16x16x32_bf16(
                    Abuf[slot][ms], Bbuf[slot][nt], acc[ms][nt], 0, 0, 0);
        if (s + 3 < 18) ISSUE(s + 3, slot)
    }
#undef ISSUE

    // Epilogue: C/D layout col=lane&15 (n), row=quad*4+reg (m). Nontemporal f32x4 stores.
#pragma unroll
    for (int nt = 0; nt < 4; ++nt) {
        int o = nt * 16 + col;
        float bv = bias[o];
#pragma unroll
        for (int ms = 0; ms < 2; ++ms) {
            int m0 = ms * 16 + quad * 4;
            int hw0 = (gbase + pxw + m0) & (HW_ - 1);
            f32x4_t v = acc[ms][nt];
            v.x += bv; v.y += bv; v.z += bv; v.w += bv;
            __builtin_nontemporal_store(v,
                (f32x4_t*)(out + (((size_t)(b * 64 + o)) << 17) + hw0));
        }
    }
}

// ---------------------------------------------------------------------------
// Fallback path (ws too small): direct fp32, slow but correct, no workspace.
// ---------------------------------------------------------------------------
__global__ __launch_bounds__(256) void k_fallback(const float* __restrict__ x,
                                                  const int* __restrict__ idx,
                                                  const float* __restrict__ w,
                                                  const float* __restrict__ bias,
                                                  float* __restrict__ out) {
    size_t g = (size_t)blockIdx.x * 256 + threadIdx.x;   // (b*64+o)*HW + hw
    int hw = (int)(g & (HW_ - 1));
    int o  = (int)((g >> 17) & 63);
    int b  = (int)(g >> 23);
    int h = hw >> 9, ww = hw & (W_ - 1);
    size_t ibase = (size_t)(3 * h) * (3 * W_) + 3 * ww;
    int p[9];
#pragma unroll
    for (int th = 0; th < 3; ++th)
#pragma unroll
        for (int tw = 0; tw < 3; ++tw)
            p[th * 3 + tw] = idx[ibase + (size_t)th * (3 * W_) + tw];
    const float* xb = x + (size_t)b * C_ * HW_;
    const float* wo = w + (size_t)o * KDIM;
    float acc = bias[o];
    for (int c = 0; c < C_; ++c) {
        const float* xc = xb + (size_t)c * HW_;
        const float* wc = wo + c * 9;
#pragma unroll
        for (int t = 0; t < 9; ++t)
            acc += xc[p[t]] * wc[t];
    }
    out[g] = acc;
}

extern "C" void kernel_launch(void* const* d_in, const int* in_sizes, int n_in,
                              void* d_out, int out_size, void* d_ws, size_t ws_size,
                              hipStream_t stream) {
    const float* x    = (const float*)d_in[0];
    const int*   idx  = (const int*)d_in[1];     // harness delivers integer inputs as int32
    const float* w    = (const float*)d_in[2];
    const float* bias = (const float*)d_in[3];
    float* out = (float*)d_out;

    if (ws_size >= XT_BYTES + WF_BYTES) {
        unsigned short* xt    = (unsigned short*)d_ws;
        unsigned short* wfrag = (unsigned short*)((char*)d_ws + XT_BYTES);
        k_prep_w   <<<18,   256, 0, stream>>>(w, wfrag);
        k_transpose<<<2048, 256, 0, stream>>>(x, xt);
        k_gemm     <<<4096, 256, 0, stream>>>(xt, wfrag, idx, bias, out);
    } else {
        k_fallback<<<131072, 256, 0, stream>>>(x, idx, w, bias, out);
    }
}

// Round 3
// 344.613 us; speedup vs baseline: 1.0281x; 1.0105x over previous
//
#include <hip/hip_runtime.h>
#include <stdint.h>

// Problem constants: x[4,64,256,512] fp32, idx[3*256*3*512] i32 (harness converts i64->i32),
// w[64,64,3,3] fp32, bias[64] fp32. out[4,64,256,512] fp32.
#define HW_   131072   // 256*512 = 1<<17
#define W_    512
#define C_    64
#define KDIM  576      // 9 taps * 64 channels

typedef __bf16 bf16_t;
typedef bf16_t bf16x8 __attribute__((ext_vector_type(8)));
typedef float  f32x4_t __attribute__((ext_vector_type(4)));
typedef float  f32x2_t __attribute__((ext_vector_type(2)));

__device__ __forceinline__ unsigned short f32_to_bf16(float f) {
    union { float f; unsigned u; } v; v.f = f;
    unsigned r = (v.u + 0x7FFFu + ((v.u >> 16) & 1u)) >> 16;  // RNE
    return (unsigned short)r;
}

// Pack two f32 -> two bf16 in one dword via compiler casts (RNE).
__device__ __forceinline__ unsigned pack_bf16(float a, float b) {
    union { unsigned u; __bf16 h[2]; } pk;
    pk.h[0] = (__bf16)a;
    pk.h[1] = (__bf16)b;
    return pk.u;
}

// ws layout: xt bf16 [B*HW][64] at offset 0 (67,108,864 B); Wfrag bf16 at +XT_BYTES (73,728 B)
#define XT_BYTES   67108864ull
#define WF_BYTES   73728ull

// ---------------------------------------------------------------------------
// Pack weight[o][c][kh][kw] fp32 -> B-operand fragments, K-order k = t*64 + c, t = kh*3+kw.
// Fragment (kc, nt): lane L holds B[k = kc*32 + (L>>4)*8 + j][n = nt*16 + (L&15)], j=0..7.
// ---------------------------------------------------------------------------
__global__ __launch_bounds__(256) void k_prep_w(const float* __restrict__ w,
                                                unsigned short* __restrict__ wfrag) {
    int id = blockIdx.x * 256 + threadIdx.x;   // (kc*4 + nt)*64 + lane, total 18*4*64 = 4608
    if (id >= 18 * 4 * 64) return;
    int lane = id & 63;
    int nt   = (id >> 6) & 3;
    int kc   = id >> 8;
    int n  = nt * 16 + (lane & 15);
    int k0 = kc * 32 + ((lane >> 4) << 3);
    unsigned short tmp[8];
#pragma unroll
    for (int j = 0; j < 8; ++j) {
        int k = k0 + j;
        int t = k >> 6;    // tap 0..8
        int c = k & 63;
        tmp[j] = f32_to_bf16(w[(size_t)n * KDIM + c * 9 + t]);
    }
    uint4 v;
    v.x = tmp[0] | ((unsigned)tmp[1] << 16);
    v.y = tmp[2] | ((unsigned)tmp[3] << 16);
    v.z = tmp[4] | ((unsigned)tmp[5] << 16);
    v.w = tmp[6] | ((unsigned)tmp[7] << 16);
    ((uint4*)wfrag)[id] = v;
}

// ---------------------------------------------------------------------------
// Transpose + convert via LDS: x[b][c][p] fp32 -> xt[(b*HW+p)][c] bf16.
// Phase 1: float2 nontemporal reads (8 B/lane), packed bf16 convert, ds_write_b32.
// Phase 2: row-major reads, coalesced lane-contiguous 16 B stores.
// x is read exactly once -> nontemporal loads keep L2/L3 space for xt (gemm re-reads it).
// ---------------------------------------------------------------------------
__global__ __launch_bounds__(256) void k_transpose(const float* __restrict__ x,
                                                   unsigned short* __restrict__ xt) {
    __shared__ unsigned short tile[256][66];
    int t    = threadIdx.x;
    int lane = t & 63;
    int wave = t >> 6;
    int gp0 = blockIdx.x * 256;                // grid = 2048
    int b  = gp0 >> 17;
    int p0 = gp0 & (HW_ - 1);
    const float* xb = x + ((size_t)b * C_) * HW_ + p0;
#pragma unroll
    for (int it = 0; it < 16; ++it) {
        int c0  = (it & 7) * 8 + wave * 2;     // even channels 0..62, 2 per thread
        int px0 = ((it >> 3) << 7) + lane * 2; // 2 consecutive pixels per thread
        const float* s0 = xb + ((size_t)c0 << 17) + px0;
        f32x2_t v0 = __builtin_nontemporal_load((const f32x2_t*)s0);
        f32x2_t v1 = __builtin_nontemporal_load((const f32x2_t*)(s0 + HW_));
        *(unsigned*)&tile[px0 + 0][c0] = pack_bf16(v0.x, v1.x);
        *(unsigned*)&tile[px0 + 1][c0] = pack_bf16(v0.y, v1.y);
    }
    __syncthreads();
    unsigned short* dst = xt + (size_t)gp0 * C_;
#pragma unroll
    for (int it = 0; it < 8; ++it) {
        int cid = it * 256 + t;        // 2048 chunks of 16 B
        int px  = cid >> 3;
        int ch  = cid & 7;
        uint4 v;
        v.x = *(unsigned*)&tile[px][ch * 8 + 0];
        v.y = *(unsigned*)&tile[px][ch * 8 + 2];
        v.z = *(unsigned*)&tile[px][ch * 8 + 4];
        v.w = *(unsigned*)&tile[px][ch * 8 + 6];
        ((uint4*)(dst + (size_t)px * C_))[ch] = v;   // lane-contiguous across the wave
    }
}

// ---------------------------------------------------------------------------
// Gather-GEMM, deep-pipelined. Per wave: M=32 pixels x N=64, K=576 (18 half-K steps).
// The gather (A operand) is random over the 16.8 MB batch image -> L2 misses with
// ~500-900 cyc latency; this is the bottleneck (round-2 PMC: MfmaUtil 11%, VALU 7%,
// hbm 38%). VGPR_Count=48 showed the old 3-slot rotation was collapsed by the
// compiler. v3: A-gather pipeline depth 9 (Abuf[9][2] = 72 VGPR, refill slot s%9
// after use -> issue-to-use = 9 steps ~= 1080 cyc wall at 3 waves/SIMD), B (L2-hot
// weights) depth 2. __launch_bounds__(256,3) pins 3 waves/SIMD (VGPR cap ~170).
// Grid 4096 x 256 threads; block = 128 consecutive pixels (same batch).
// XCD-chunked bijective swizzle: co-resident blocks per XCD share one batch image.
// ---------------------------------------------------------------------------
__global__ __launch_bounds__(256, 3) void k_gemm(const unsigned short* __restrict__ xt,
                                                 const unsigned short* __restrict__ wfrag,
                                                 const int* __restrict__ idx,
                                                 const float* __restrict__ bias,
                                                 float* __restrict__ out) {
    __shared__ unsigned p_lds[128][9];   // 4608 B

    int tid  = threadIdx.x;
    int wave = tid >> 6;
    int lane = tid & 63;
    int bid  = blockIdx.x;
    int gbase = (((bid & 7) << 9) + (bid >> 3)) * 128;  // XCD-chunked swizzle (4096%8==0)
    int b = gbase >> 17;

    // Stage gather indices: 2 threads per pixel (128 px * 9 taps)
    {
        int px   = tid >> 1;
        int half = tid & 1;
        int g  = gbase + px;
        int hw = g & (HW_ - 1);
        int h = hw >> 9, w = hw & (W_ - 1);
        size_t base = (size_t)(3 * h) * (3 * W_) + 3 * w;
        if (half == 0) {
#pragma unroll
            for (int t = 0; t < 5; ++t)
                p_lds[px][t] = (unsigned)idx[base + (size_t)(t / 3) * (3 * W_) + (t % 3)];
        } else {
#pragma unroll
            for (int t = 5; t < 9; ++t)
                p_lds[px][t] = (unsigned)idx[base + (size_t)(t / 3) * (3 * W_) + (t % 3)];
        }
    }
    __syncthreads();

    int quad = lane >> 4;
    int col  = lane & 15;
    int pxw  = wave * 32;

    // Hoist this lane's 18 gather indices into registers
    unsigned p_reg[9][2];
#pragma unroll
    for (int t = 0; t < 9; ++t) {
        p_reg[t][0] = p_lds[pxw + col][t];
        p_reg[t][1] = p_lds[pxw + 16 + col][t];
    }

    const unsigned short* xtb = xt + (((size_t)b) << 17) * C_;
    const uint4* wf = (const uint4*)wfrag;

    f32x4_t acc[2][4] = {};
    bf16x8 Abuf[9][2];   // 72 VGPR: depth-9 gather pipeline
    bf16x8 Bbuf[2][4];   // 32 VGPR: depth-2, L2-hot

    // A step s: frag per ms at row p_reg[s>>1][ms], byte off (s&1)*64 + quad*16
#define ISSUE_A(s, slot)                                                            \
    {                                                                               \
        const int t_ = (s) >> 1, h_ = (s) & 1;                                      \
        _Pragma("unroll")                                                           \
        for (int ms = 0; ms < 2; ++ms) {                                            \
            const uint4* ap = (const uint4*)((const char*)xtb +                     \
                ((size_t)p_reg[t_][ms] << 7) + (h_ << 6) + (quad << 4));            \
            Abuf[slot][ms] = __builtin_bit_cast(bf16x8, *ap);                       \
        }                                                                           \
    }
#define ISSUE_B(s, slot)                                                            \
    {                                                                               \
        _Pragma("unroll")                                                           \
        for (int nt = 0; nt < 4; ++nt)                                              \
            Bbuf[slot][nt] = __builtin_bit_cast(bf16x8, wf[((s) * 4 + nt) * 64 + lane]); \
    }

    // Prologue: fill the whole A pipeline, 2 B stages
    ISSUE_A(0, 0) ISSUE_A(1, 1) ISSUE_A(2, 2) ISSUE_A(3, 3) ISSUE_A(4, 4)
    ISSUE_A(5, 5) ISSUE_A(6, 6) ISSUE_A(7, 7) ISSUE_A(8, 8)
    ISSUE_B(0, 0) ISSUE_B(1, 1)

#pragma unroll
    for (int s = 0; s < 18; ++s) {
        const int sa = s % 9;
        const int sb = s % 2;
#pragma unroll
        for (int ms = 0; ms < 2; ++ms)
#pragma unroll
            for (int nt = 0; nt < 4; ++nt)
                acc[ms][nt] = __builtin_amdgcn_mfma_f32_16x16x32_bf16(
                    Abuf[sa][ms], Bbuf[sb][nt], acc[ms][nt], 0, 0, 0);
        // refill the slots just consumed
        if (s + 9 < 18) ISSUE_A(s + 9, sa)
        if (s + 2 < 18) ISSUE_B(s + 2, sb)
    }
#undef ISSUE_A
#undef ISSUE_B

    // Epilogue: C/D layout col=lane&15 (n), row=quad*4+reg (m). Plain f32x4 stores
    // (nontemporal regressed: WRITE_SIZE 131->168 MB, round 2).
#pragma unroll
    for (int nt = 0; nt < 4; ++nt) {
        int o = nt * 16 + col;
        float bv = bias[o];
#pragma unroll
        for (int ms = 0; ms < 2; ++ms) {
            int m0 = ms * 16 + quad * 4;
            int hw0 = (gbase + pxw + m0) & (HW_ - 1);
            f32x4_t v = acc[ms][nt];
            v.x += bv; v.y += bv; v.z += bv; v.w += bv;
            *(f32x4_t*)(out + (((size_t)(b * 64 + o)) << 17) + hw0) = v;
        }
    }
}

// ---------------------------------------------------------------------------
// Fallback path (ws too small): direct fp32, slow but correct, no workspace.
// ---------------------------------------------------------------------------
__global__ __launch_bounds__(256) void k_fallback(const float* __restrict__ x,
                                                  const int* __restrict__ idx,
                                                  const float* __restrict__ w,
                                                  const float* __restrict__ bias,
                                                  float* __restrict__ out) {
    size_t g = (size_t)blockIdx.x * 256 + threadIdx.x;   // (b*64+o)*HW + hw
    int hw = (int)(g & (HW_ - 1));
    int o  = (int)((g >> 17) & 63);
    int b  = (int)(g >> 23);
    int h = hw >> 9, ww = hw & (W_ - 1);
    size_t ibase = (size_t)(3 * h) * (3 * W_) + 3 * ww;
    int p[9];
#pragma unroll
    for (int th = 0; th < 3; ++th)
#pragma unroll
        for (int tw = 0; tw < 3; ++tw)
            p[th * 3 + tw] = idx[ibase + (size_t)th * (3 * W_) + tw];
    const float* xb = x + (size_t)b * C_ * HW_;
    const float* wo = w + (size_t)o * KDIM;
    float acc = bias[o];
    for (int c = 0; c < C_; ++c) {
        const float* xc = xb + (size_t)c * HW_;
        const float* wc = wo + c * 9;
#pragma unroll
        for (int t = 0; t < 9; ++t)
            acc += xc[p[t]] * wc[t];
    }
    out[g] = acc;
}

extern "C" void kernel_launch(void* const* d_in, const int* in_sizes, int n_in,
                              void* d_out, int out_size, void* d_ws, size_t ws_size,
                              hipStream_t stream) {
    const float* x    = (const float*)d_in[0];
    const int*   idx  = (const int*)d_in[1];     // harness delivers integer inputs as int32
    const float* w    = (const float*)d_in[2];
    const float* bias = (const float*)d_in[3];
    float* out = (float*)d_out;

    if (ws_size >= XT_BYTES + WF_BYTES) {
        unsigned short* xt    = (unsigned short*)d_ws;
        unsigned short* wfrag = (unsigned short*)((char*)d_ws + XT_BYTES);
        k_prep_w   <<<18,   256, 0, stream>>>(w, wfrag);
        k_transpose<<<2048, 256, 0, stream>>>(x, xt);
        k_gemm     <<<4096, 256, 0, stream>>>(xt, wfrag, idx, bias, out);
    } else {
        k_fallback<<<131072, 256, 0, stream>>>(x, idx, w, bias, out);
    }
}

// Round 4
// 329.840 us; speedup vs baseline: 1.0742x; 1.0448x over previous
//
#include <hip/hip_runtime.h>
#include <stdint.h>

// Problem constants: x[4,64,256,512] fp32, idx[3*256*3*512] i32 (harness converts i64->i32),
// w[64,64,3,3] fp32, bias[64] fp32. out[4,64,256,512] fp32.
#define HW_   131072   // 256*512 = 1<<17
#define W_    512
#define C_    64
#define KDIM  576      // 9 taps * 64 channels

typedef __bf16 bf16_t;
typedef bf16_t bf16x8 __attribute__((ext_vector_type(8)));
typedef float  f32x4_t __attribute__((ext_vector_type(4)));
typedef float  f32x2_t __attribute__((ext_vector_type(2)));
typedef unsigned u32x4 __attribute__((ext_vector_type(4)));

__device__ __forceinline__ unsigned short f32_to_bf16(float f) {
    union { float f; unsigned u; } v; v.f = f;
    unsigned r = (v.u + 0x7FFFu + ((v.u >> 16) & 1u)) >> 16;  // RNE
    return (unsigned short)r;
}

// Pack two f32 -> two bf16 in one dword via compiler casts (RNE).
__device__ __forceinline__ unsigned pack_bf16(float a, float b) {
    union { unsigned u; __bf16 h[2]; } pk;
    pk.h[0] = (__bf16)a;
    pk.h[1] = (__bf16)b;
    return pk.u;
}

// ws layout: xt bf16 [B*HW][64] at offset 0 (67,108,864 B); Wfrag bf16 at +XT_BYTES (73,728 B)
#define XT_BYTES   67108864ull
#define WF_BYTES   73728ull

// ---------------------------------------------------------------------------
// Pack weight[o][c][kh][kw] fp32 -> B-operand fragments, K-order k = t*64 + c, t = kh*3+kw.
// Fragment (kc, nt): lane L holds B[k = kc*32 + (L>>4)*8 + j][n = nt*16 + (L&15)], j=0..7.
// ---------------------------------------------------------------------------
__global__ __launch_bounds__(256) void k_prep_w(const float* __restrict__ w,
                                                unsigned short* __restrict__ wfrag) {
    int id = blockIdx.x * 256 + threadIdx.x;   // (kc*4 + nt)*64 + lane, total 18*4*64 = 4608
    if (id >= 18 * 4 * 64) return;
    int lane = id & 63;
    int nt   = (id >> 6) & 3;
    int kc   = id >> 8;
    int n  = nt * 16 + (lane & 15);
    int k0 = kc * 32 + ((lane >> 4) << 3);
    unsigned short tmp[8];
#pragma unroll
    for (int j = 0; j < 8; ++j) {
        int k = k0 + j;
        int t = k >> 6;    // tap 0..8
        int c = k & 63;
        tmp[j] = f32_to_bf16(w[(size_t)n * KDIM + c * 9 + t]);
    }
    uint4 v;
    v.x = tmp[0] | ((unsigned)tmp[1] << 16);
    v.y = tmp[2] | ((unsigned)tmp[3] << 16);
    v.z = tmp[4] | ((unsigned)tmp[5] << 16);
    v.w = tmp[6] | ((unsigned)tmp[7] << 16);
    ((uint4*)wfrag)[id] = v;
}

// ---------------------------------------------------------------------------
// Transpose + convert via LDS: x[b][c][p] fp32 -> xt[(b*HW+p)][c] bf16.
// (frozen this round so its true duration surfaces in the profile)
// ---------------------------------------------------------------------------
__global__ __launch_bounds__(256) void k_transpose(const float* __restrict__ x,
                                                   unsigned short* __restrict__ xt) {
    __shared__ unsigned short tile[256][66];
    int t    = threadIdx.x;
    int lane = t & 63;
    int wave = t >> 6;
    int gp0 = blockIdx.x * 256;                // grid = 2048
    int b  = gp0 >> 17;
    int p0 = gp0 & (HW_ - 1);
    const float* xb = x + ((size_t)b * C_) * HW_ + p0;
#pragma unroll
    for (int it = 0; it < 16; ++it) {
        int c0  = (it & 7) * 8 + wave * 2;     // even channels 0..62, 2 per thread
        int px0 = ((it >> 3) << 7) + lane * 2; // 2 consecutive pixels per thread
        const float* s0 = xb + ((size_t)c0 << 17) + px0;
        f32x2_t v0 = __builtin_nontemporal_load((const f32x2_t*)s0);
        f32x2_t v1 = __builtin_nontemporal_load((const f32x2_t*)(s0 + HW_));
        *(unsigned*)&tile[px0 + 0][c0] = pack_bf16(v0.x, v1.x);
        *(unsigned*)&tile[px0 + 1][c0] = pack_bf16(v0.y, v1.y);
    }
    __syncthreads();
    unsigned short* dst = xt + (size_t)gp0 * C_;
#pragma unroll
    for (int it = 0; it < 8; ++it) {
        int cid = it * 256 + t;        // 2048 chunks of 16 B
        int px  = cid >> 3;
        int ch  = cid & 7;
        uint4 v;
        v.x = *(unsigned*)&tile[px][ch * 8 + 0];
        v.y = *(unsigned*)&tile[px][ch * 8 + 2];
        v.z = *(unsigned*)&tile[px][ch * 8 + 4];
        v.w = *(unsigned*)&tile[px][ch * 8 + 6];
        ((uint4*)(dst + (size_t)px * C_))[ch] = v;   // lane-contiguous across the wave
    }
}

// ---------------------------------------------------------------------------
// Gather-GEMM v4: ISA-enforced depth-8 gather pipeline.
// Rounds 2/3 proved the compiler collapses any C++-level register rotation
// (VGPR stayed 48-52, MfmaUtil 11%). v4 makes every K-loop gather an
// asm-volatile global_load_dwordx4 with exact counted s_waitcnt vmcnt(N)
// (+ sched_barrier(0) per rule #18). To keep the vmcnt FIFO pure-A:
//  - B fragments for steps 0..15 live in LDS (64 KiB, staged once per block,
//    read per step as ping-pong ds_read_b128 -> lgkmcnt, not vmcnt);
//  - B for steps 16/17 ride the asm FIFO first and drain at the first wait;
//  - gather indices are loaded per-lane directly (drained by the staging
//    __syncthreads, which leaves the vmem FIFO empty).
// Depth 8 => 7 steps x 2 loads in flight => ~700+ cyc latency coverage/wave.
// Cost: 2 blocks/CU (LDS), ~200 VGPR (2 waves/SIMD). Bet: MLP >> lost TLP.
// ---------------------------------------------------------------------------
__global__ __launch_bounds__(256, 2) void k_gemm(const unsigned short* __restrict__ xt,
                                                 const unsigned short* __restrict__ wfrag,
                                                 const int* __restrict__ idx,
                                                 const float* __restrict__ bias,
                                                 float* __restrict__ out) {
    __shared__ u32x4 blds[4096];   // 65536 B: B-frags for kc = 0..15

    int tid  = threadIdx.x;
    int wave = tid >> 6;
    int lane = tid & 63;
    int bid  = blockIdx.x;
    int gbase = (((bid & 7) << 9) + (bid >> 3)) * 128;  // XCD-chunked swizzle (4096%8==0)
    int b = gbase >> 17;

    int quad = lane >> 4;
    int col  = lane & 15;
    int pxw  = wave * 32;

    // ---- stage B fragments (kc 0..15) into LDS; coalesced 16B loads ----
    {
        const u32x4* wfv = (const u32x4*)wfrag;
#pragma unroll
        for (int i = 0; i < 16; ++i)
            blds[i * 256 + tid] = wfv[i * 256 + tid];
    }

    // ---- gather indices: per-lane direct loads (no LDS) ----
    unsigned p_reg[9][2];
#pragma unroll
    for (int ms = 0; ms < 2; ++ms) {
        int g  = gbase + pxw + ms * 16 + col;
        int hw = g & (HW_ - 1);
        int h = hw >> 9, w = hw & (W_ - 1);
        const int* ib = idx + (size_t)(3 * h) * (3 * W_) + 3 * w;
#pragma unroll
        for (int t = 0; t < 9; ++t)
            p_reg[t][ms] = (unsigned)ib[(t / 3) * (3 * W_) + (t % 3)];
    }

    __syncthreads();   // drains ALL compiler vmem loads -> vmcnt FIFO empty

    const unsigned short* xtb = xt + (((size_t)b) << 17) * C_;

    f32x4_t acc[2][4] = {};
    u32x4 Abuf[8][2];   // depth-8 asm pipeline
    u32x4 Bp[2][4];     // ping-pong LDS B fragments
    u32x4 Bt[2][4];     // B for steps 16,17 (asm FIFO head, drains at first wait)

#define GLOADX4(dst, addr)                                                       \
    asm volatile("global_load_dwordx4 %0, %1, off"                               \
                 : "=&v"(dst) : "v"((const void*)(addr)) : "memory")
#define WAITVM(n)                                                                \
    { asm volatile("s_waitcnt vmcnt(" #n ")" ::: "memory");                      \
      __builtin_amdgcn_sched_barrier(0); }
#define ISSUE_A(s)                                                               \
    { const int t_ = (s) >> 1, h_ = (s) & 1;                                     \
      GLOADX4(Abuf[(s) & 7][0], (const char*)xtb +                               \
              (((size_t)p_reg[t_][0] << 7) + (h_ << 6) + (quad << 4)));          \
      GLOADX4(Abuf[(s) & 7][1], (const char*)xtb +                               \
              (((size_t)p_reg[t_][1] << 7) + (h_ << 6) + (quad << 4))); }
#define READ_B(s)                                                                \
    { _Pragma("unroll")                                                          \
      for (int nt = 0; nt < 4; ++nt)                                             \
          Bp[(s) & 1][nt] = blds[((s) * 4 + nt) * 64 + lane]; }
#define MFMA8(s, BSRC)                                                           \
    { _Pragma("unroll")                                                          \
      for (int ms = 0; ms < 2; ++ms)                                             \
      _Pragma("unroll")                                                          \
      for (int nt = 0; nt < 4; ++nt)                                             \
          acc[ms][nt] = __builtin_amdgcn_mfma_f32_16x16x32_bf16(                 \
              __builtin_bit_cast(bf16x8, Abuf[(s) & 7][ms]),                     \
              __builtin_bit_cast(bf16x8, (BSRC)[nt]), acc[ms][nt], 0, 0, 0); }

    // ---- asm FIFO prologue ----
    // B tail (steps 16,17): 8 loads, FIFO head -> retired by the first WAITVM(14).
    {
        const char* wfb = (const char*)wfrag;
#pragma unroll
        for (int nt = 0; nt < 4; ++nt)
            GLOADX4(Bt[0][nt], wfb + (size_t)((16 * 4 + nt) * 64 + lane) * 16);
#pragma unroll
        for (int nt = 0; nt < 4; ++nt)
            GLOADX4(Bt[1][nt], wfb + (size_t)((17 * 4 + nt) * 64 + lane) * 16);
    }
    // A pipeline fill: steps 0..7 (16 loads)
    ISSUE_A(0) ISSUE_A(1) ISSUE_A(2) ISSUE_A(3)
    ISSUE_A(4) ISSUE_A(5) ISSUE_A(6) ISSUE_A(7)

    READ_B(0)   // Bcur for step 0 (LDS)

    // ---- 18 steps, hand-unrolled with exact vmcnt counts ----
    // steady state: outstanding after wait = 7 A-steps x 2 = 14
    WAITVM(14) READ_B(1)  MFMA8(0,  Bp[0]) ISSUE_A(8)
    WAITVM(14) READ_B(2)  MFMA8(1,  Bp[1]) ISSUE_A(9)
    WAITVM(14) READ_B(3)  MFMA8(2,  Bp[0]) ISSUE_A(10)
    WAITVM(14) READ_B(4)  MFMA8(3,  Bp[1]) ISSUE_A(11)
    WAITVM(14) READ_B(5)  MFMA8(4,  Bp[0]) ISSUE_A(12)
    WAITVM(14) READ_B(6)  MFMA8(5,  Bp[1]) ISSUE_A(13)
    WAITVM(14) READ_B(7)  MFMA8(6,  Bp[0]) ISSUE_A(14)
    WAITVM(14) READ_B(8)  MFMA8(7,  Bp[1]) ISSUE_A(15)
    WAITVM(14) READ_B(9)  MFMA8(8,  Bp[0]) ISSUE_A(16)
    WAITVM(14) READ_B(10) MFMA8(9,  Bp[1]) ISSUE_A(17)
    WAITVM(14) READ_B(11) MFMA8(10, Bp[0])
    WAITVM(12) READ_B(12) MFMA8(11, Bp[1])
    WAITVM(10) READ_B(13) MFMA8(12, Bp[0])
    WAITVM(8)  READ_B(14) MFMA8(13, Bp[1])
    WAITVM(6)  READ_B(15) MFMA8(14, Bp[0])
    WAITVM(4)             MFMA8(15, Bp[1])
    WAITVM(2)             MFMA8(16, Bt[0])
    WAITVM(0)             MFMA8(17, Bt[1])

#undef GLOADX4
#undef WAITVM
#undef ISSUE_A
#undef READ_B
#undef MFMA8

    // Epilogue: C/D layout col=lane&15 (n), row=quad*4+reg (m). Plain f32x4 stores.
#pragma unroll
    for (int nt = 0; nt < 4; ++nt) {
        int o = nt * 16 + col;
        float bv = bias[o];
#pragma unroll
        for (int ms = 0; ms < 2; ++ms) {
            int m0 = ms * 16 + quad * 4;
            int hw0 = (gbase + pxw + m0) & (HW_ - 1);
            f32x4_t v = acc[ms][nt];
            v.x += bv; v.y += bv; v.z += bv; v.w += bv;
            *(f32x4_t*)(out + (((size_t)(b * 64 + o)) << 17) + hw0) = v;
        }
    }
}

// ---------------------------------------------------------------------------
// Fallback path (ws too small): direct fp32, slow but correct, no workspace.
// ---------------------------------------------------------------------------
__global__ __launch_bounds__(256) void k_fallback(const float* __restrict__ x,
                                                  const int* __restrict__ idx,
                                                  const float* __restrict__ w,
                                                  const float* __restrict__ bias,
                                                  float* __restrict__ out) {
    size_t g = (size_t)blockIdx.x * 256 + threadIdx.x;   // (b*64+o)*HW + hw
    int hw = (int)(g & (HW_ - 1));
    int o  = (int)((g >> 17) & 63);
    int b  = (int)(g >> 23);
    int h = hw >> 9, ww = hw & (W_ - 1);
    size_t ibase = (size_t)(3 * h) * (3 * W_) + 3 * ww;
    int p[9];
#pragma unroll
    for (int th = 0; th < 3; ++th)
#pragma unroll
        for (int tw = 0; tw < 3; ++tw)
            p[th * 3 + tw] = idx[ibase + (size_t)th * (3 * W_) + tw];
    const float* xb = x + (size_t)b * C_ * HW_;
    const float* wo = w + (size_t)o * KDIM;
    float acc = bias[o];
    for (int c = 0; c < C_; ++c) {
        const float* xc = xb + (size_t)c * HW_;
        const float* wc = wo + c * 9;
#pragma unroll
        for (int t = 0; t < 9; ++t)
            acc += xc[p[t]] * wc[t];
    }
    out[g] = acc;
}

extern "C" void kernel_launch(void* const* d_in, const int* in_sizes, int n_in,
                              void* d_out, int out_size, void* d_ws, size_t ws_size,
                              hipStream_t stream) {
    const float* x    = (const float*)d_in[0];
    const int*   idx  = (const int*)d_in[1];     // harness delivers integer inputs as int32
    const float* w    = (const float*)d_in[2];
    const float* bias = (const float*)d_in[3];
    float* out = (float*)d_out;

    if (ws_size >= XT_BYTES + WF_BYTES) {
        unsigned short* xt    = (unsigned short*)d_ws;
        unsigned short* wfrag = (unsigned short*)((char*)d_ws + XT_BYTES);
        k_prep_w   <<<18,   256, 0, stream>>>(w, wfrag);
        k_transpose<<<2048, 256, 0, stream>>>(x, xt);
        k_gemm     <<<4096, 256, 0, stream>>>(xt, wfrag, idx, bias, out);
    } else {
        k_fallback<<<131072, 256, 0, stream>>>(x, idx, w, bias, out);
    }
}